// Round 14
// baseline (233.398 us; speedup 1.0000x reference)
//
#include <hip/hip_runtime.h>
#include <hip/hip_bf16.h>

#define NPTS 100000
#define KNBR 16
#define CCH  64
#define GRP  8
#define BN_EPS 1e-5f
#define NROW (NPTS * KNBR)        // 1,600,000
#define NBATCH (NROW / 64)        // 25,000 batches of 64 rows (4 points)
#define NPB   ((NPTS + 63) / 64)  // 1563 point-batches

// ---- workspace layout (float offsets) ----
#define O_QLINH 0                  // NPTS*64 bf16 = NPTS*32 floats
#define O_KLINH (NPTS * 32)
#define O_VLINH (NPTS * 64)
#define O_STAT  (NPTS * 96)        // 416 floats of stats
#define O_AFF   (O_STAT + 416)     // 416 floats of affines
#define O_W2W1  (O_AFF + 416)      // 512 floats: wp2@ww1 [64][8]
#define O_BW1E  (O_W2W1 + 512)     // 8 floats: bw1 + bp2@ww1
#define O_QW1   (O_BW1E + 8)       // NPTS*8 fp32
#define O_KW1   (O_QW1 + NPTS * 8) // NPTS*8 fp32
#define O_W1H   (O_KW1 + NPTS * 8) // NROW*8 bf16 = NROW*4 floats (25.6 MB)

typedef __attribute__((ext_vector_type(8))) short short8;
typedef __attribute__((ext_vector_type(4))) short short4v;
typedef __attribute__((ext_vector_type(4))) float f32x4;
#define MFMA16(a, b, c) __builtin_amdgcn_mfma_f32_16x16x32_bf16(a, b, c, 0, 0, 0)

__device__ __forceinline__ int clip_idx(int r) {
    int i = r < 0 ? 0 : r;
    return i >= NPTS ? NPTS - 1 : i;
}
__device__ __forceinline__ unsigned short f2bf(float x) {
    union { float f; unsigned u; } v; v.f = x;
    unsigned r = v.u + 0x7fffu + ((v.u >> 16) & 1u);
    return (unsigned short)(r >> 16);
}
__device__ __forceinline__ float bf2f(unsigned short h) {
    union { unsigned u; float f; } v; v.u = ((unsigned)h) << 16;
    return v.f;
}
// packed f32x2 -> bf16x2 (single HW instruction; no builtin on gfx950)
__device__ __forceinline__ unsigned pk_bf16(float lo, float hi) {
    unsigned r;
    asm("v_cvt_pk_bf16_f32 %0, %1, %2" : "=v"(r) : "v"(lo), "v"(hi));
    return r;
}
// K-slot s -> physical short offset within a row (A-fragment-linear order)
__device__ __forceinline__ int physK(int s) {
    return (s >> 5) * 32 + ((s >> 2) & 3) * 8 + ((s >> 4) & 1) * 4 + (s & 3);
}
// short index into a [64 rows][64 K-slots] A-buffer with 16B-chunk XOR swizzle
__device__ __forceinline__ int aOff(int r, int p) {
    return r * 64 + (((p >> 3) ^ (r & 7)) << 3) + (p & 7);
}
// element i of a B fragment for quarter q: K-in-block index
__device__ __forceinline__ int kib_of(int i, int q) {
    return (i < 4) ? (4 * q + i) : (16 + 4 * q + (i - 4));
}

// ---- prep: zero stats + w2w1 = wp2@ww1 + bw1e = bw1 + bp2@ww1 ----
__global__ __launch_bounds__(512) void k_prep(
    const float* __restrict__ wp2, const float* __restrict__ ww1,
    const float* __restrict__ bw1, const float* __restrict__ bp2,
    float* __restrict__ stat, float* __restrict__ w2w1, float* __restrict__ bw1e)
{
    int t = threadIdx.x;
    if (t < 416) stat[t] = 0.f;
    int j = t >> 3, g = t & 7;
    float acc = 0.f;
    #pragma unroll 16
    for (int c = 0; c < 64; ++c) acc = fmaf(wp2[j * 64 + c], ww1[c * 8 + g], acc);
    w2w1[t] = acc;
    if (t < 8) {
        float b = bw1[t];
        #pragma unroll 16
        for (int c = 0; c < 64; ++c) b = fmaf(bp2[c], ww1[c * 8 + t], b);
        bw1e[t] = b;
    }
}

// ---- Q/K/V projection via MFMA + Q/K BN stats; pmom fused as extra blocks ----
#define QKV_BLOCKS 512
__global__ __launch_bounds__(256) void k_qkv(
    const float* __restrict__ feat,
    const float* __restrict__ wq, const float* __restrict__ bq,
    const float* __restrict__ wk, const float* __restrict__ bk,
    const float* __restrict__ wv, const float* __restrict__ bv,
    const float* __restrict__ bp2,
    const float* __restrict__ coord, const int* __restrict__ ref,
    short* __restrict__ QlinH, short* __restrict__ KlinH, short* __restrict__ VlinH,
    float* __restrict__ stat)
{
    __shared__ short sA[4096];
    __shared__ float s_red[9];
    const int tid = threadIdx.x, lane = tid & 63, w = tid >> 6;
    const int q = lane >> 4, c15 = lane & 15;

    if (blockIdx.x >= QKV_BLOCKS) {
        // ---- pmom body ----
        float m[9];
        #pragma unroll
        for (int i = 0; i < 9; ++i) m[i] = 0.f;
        const int gid = (blockIdx.x - QKV_BLOCKS) * 256 + tid;
        const int stride = 128 * 256;
        for (int row = gid; row < NROW; row += stride) {
            int n = row >> 4;
            int idx = clip_idx(ref[row]);
            float px = coord[idx * 3 + 0] - coord[n * 3 + 0];
            float py = coord[idx * 3 + 1] - coord[n * 3 + 1];
            float pz = coord[idx * 3 + 2] - coord[n * 3 + 2];
            m[0] += px; m[1] += py; m[2] += pz;
            m[3] = fmaf(px, px, m[3]); m[4] = fmaf(py, py, m[4]); m[5] = fmaf(pz, pz, m[5]);
            m[6] = fmaf(px, py, m[6]); m[7] = fmaf(px, pz, m[7]); m[8] = fmaf(py, pz, m[8]);
        }
        if (tid < 9) s_red[tid] = 0.f;
        __syncthreads();
        #pragma unroll
        for (int off = 32; off >= 1; off >>= 1) {
            #pragma unroll
            for (int i = 0; i < 9; ++i) m[i] += __shfl_xor(m[i], off, 64);
        }
        if (lane == 0) {
            #pragma unroll
            for (int i = 0; i < 9; ++i) atomicAdd(&s_red[i], m[i]);
        }
        __syncthreads();
        if (tid < 9) atomicAdd(&stat[256 + tid], s_red[tid]);
        return;
    }

    // B fragments + bias: wave w owns col-tile w of wq, wk, wv
    const int colg = w * 16 + c15;
    short8 bfrag[3][2];
    float bias[3];
    {
        const float* Ws[3] = {wq, wk, wv};
        bias[0] = bq[colg];
        bias[1] = bk[colg];
        bias[2] = bv[colg] + bp2[colg];
        #pragma unroll
        for (int t = 0; t < 3; ++t) {
            #pragma unroll
            for (int kt = 0; kt < 2; ++kt) {
                short8 bb;
                #pragma unroll
                for (int i = 0; i < 8; ++i) {
                    int kk = kt * 32 + kib_of(i, q);
                    bb[i] = (short)f2bf(Ws[t][kk * 64 + colg]);
                }
                bfrag[t][kt] = bb;
            }
        }
    }
    float qs = 0.f, qs2 = 0.f, ks = 0.f, ks2 = 0.f;

    const int c4 = c15 * 4;              // 4-channel group
    const int pk4 = physK(c4);           // contiguous 4 slots

    for (int b = blockIdx.x; b < NPB; b += QKV_BLOCKS) {
        const int pbase = b * 64;
        // staging: float4 loads, 4 rows per instr
        #pragma unroll
        for (int i = 0; i < 4; ++i) {
            int p = w * 16 + i * 4 + q;
            int n = pbase + p;
            float4 v = make_float4(0.f, 0.f, 0.f, 0.f);
            if (n < NPTS) v = *(const float4*)(feat + n * 64 + c4);
            short4v h;
            h[0] = (short)f2bf(v.x); h[1] = (short)f2bf(v.y);
            h[2] = (short)f2bf(v.z); h[3] = (short)f2bf(v.w);
            *(short4v*)(sA + aOff(p, pk4)) = h;
        }
        __syncthreads();
        #pragma unroll
        for (int mt = 0; mt < 4; ++mt) {
            int r = mt * 16 + c15;
            int ch0 = q ^ (r & 7);
            int ch1 = (4 + q) ^ (r & 7);
            short8 a0 = *(const short8*)(sA + r * 64 + (ch0 << 3));
            short8 a1 = *(const short8*)(sA + r * 64 + (ch1 << 3));
            #pragma unroll
            for (int t = 0; t < 3; ++t) {
                f32x4 acc = (f32x4){0.f, 0.f, 0.f, 0.f};
                acc = MFMA16(a0, bfrag[t][0], acc);
                acc = MFMA16(a1, bfrag[t][1], acc);
                #pragma unroll
                for (int rg = 0; rg < 4; ++rg) {
                    int row = mt * 16 + 4 * q + rg;
                    int n = pbase + row;
                    if (n < NPTS) {
                        unsigned short h = f2bf(acc[rg] + bias[t]);
                        if (t == 0) {
                            QlinH[n * 64 + colg] = (short)h;
                            float vr = bf2f(h);
                            qs += vr; qs2 = fmaf(vr, vr, qs2);
                        } else if (t == 1) {
                            KlinH[n * 64 + colg] = (short)h;
                            float vr = bf2f(h);
                            ks += vr; ks2 = fmaf(vr, vr, ks2);
                        } else {
                            VlinH[n * 64 + colg] = (short)h;
                        }
                    }
                }
            }
        }
        __syncthreads();
    }
    qs += __shfl_xor(qs, 16, 64);  qs += __shfl_xor(qs, 32, 64);
    qs2 += __shfl_xor(qs2, 16, 64); qs2 += __shfl_xor(qs2, 32, 64);
    ks += __shfl_xor(ks, 16, 64);  ks += __shfl_xor(ks, 32, 64);
    ks2 += __shfl_xor(ks2, 16, 64); ks2 += __shfl_xor(ks2, 32, 64);
    if (q == 0) {
        atomicAdd(&stat[colg], qs);
        atomicAdd(&stat[64 + colg], qs2);
        atomicAdd(&stat[128 + colg], ks);
        atomicAdd(&stat[192 + colg], ks2);
    }
}

// ---- finalize q/k/p BN affines ----
__global__ __launch_bounds__(192) void k_finA(
    const float* __restrict__ gq, const float* __restrict__ betaq,
    const float* __restrict__ gk, const float* __restrict__ betak,
    const float* __restrict__ gp, const float* __restrict__ betap,
    const float* __restrict__ wp1, const float* __restrict__ bp1,
    const float* __restrict__ stat, float* __restrict__ aff)
{
    int t = threadIdx.x;
    if (t < 64) {
        float m = stat[t] / (float)NPTS;
        float v = stat[64 + t] / (float)NPTS - m * m;
        float a = gq[t] * rsqrtf(v + BN_EPS);
        aff[t] = a;
        aff[64 + t] = betaq[t] - m * a;
    } else if (t < 128) {
        int c = t - 64;
        float m = stat[128 + c] / (float)NPTS;
        float v = stat[192 + c] / (float)NPTS - m * m;
        float a = gk[c] * rsqrtf(v + BN_EPS);
        aff[128 + c] = a;
        aff[192 + c] = betak[c] - m * a;
    } else {
        int c = t - 128;
        const float R = (float)NROW;
        float Ex = stat[256] / R, Ey = stat[257] / R, Ez = stat[258] / R;
        float Exx = stat[259] / R, Eyy = stat[260] / R, Ezz = stat[261] / R;
        float Exy = stat[262] / R, Exz = stat[263] / R, Eyz = stat[264] / R;
        float Cxx = Exx - Ex * Ex, Cyy = Eyy - Ey * Ey, Czz = Ezz - Ez * Ez;
        float Cxy = Exy - Ex * Ey, Cxz = Exz - Ex * Ez, Cyz = Eyz - Ey * Ez;
        float a0 = wp1[c], a1 = wp1[64 + c], a2 = wp1[128 + c];
        float mean = a0 * Ex + a1 * Ey + a2 * Ez + bp1[c];
        float var = a0 * a0 * Cxx + a1 * a1 * Cyy + a2 * a2 * Czz
                  + 2.f * (a0 * a1 * Cxy + a0 * a2 * Cxz + a1 * a2 * Cyz);
        float a = gp[c] * rsqrtf(var + BN_EPS);
        aff[256 + c] = a;
        aff[320 + c] = betap[c] - mean * a;
    }
}

// ---- per-point QW1/KW1 = relu_bn(Q/K) @ ww1 via MFMA ----
__global__ __launch_bounds__(128) void k_qkw(
    const short* __restrict__ QlinH, const short* __restrict__ KlinH,
    const float* __restrict__ ww1, const float* __restrict__ aff,
    float* __restrict__ QW1, float* __restrict__ KW1)
{
    __shared__ short sA[2][8192];
    const int tid = threadIdx.x, lane = tid & 63, w = tid >> 6;
    const int q = lane >> 4, g = lane & 15;
    short8 bimg[2];
    #pragma unroll
    for (int kt = 0; kt < 2; ++kt) {
        short8 bb;
        #pragma unroll
        for (int i = 0; i < 8; ++i) {
            int s = kt * 32 + kib_of(i, q);
            bb[i] = (short)f2bf(g < 8 ? ww1[s * 8 + g] : 0.f);
        }
        bimg[kt] = bb;
    }
    // staging coeffs: lane handles 8 channels c8..c8+7 of 8 rows
    const int r8 = lane >> 3, c8 = (lane & 7) * 8;
    f32x4 qa0 = *(const f32x4*)(aff + c8),       qa1 = *(const f32x4*)(aff + c8 + 4);
    f32x4 qb0 = *(const f32x4*)(aff + 64 + c8),  qb1 = *(const f32x4*)(aff + 64 + c8 + 4);
    f32x4 ka0 = *(const f32x4*)(aff + 128 + c8), ka1 = *(const f32x4*)(aff + 128 + c8 + 4);
    f32x4 kb0 = *(const f32x4*)(aff + 192 + c8), kb1 = *(const f32x4*)(aff + 192 + c8 + 4);
    const int pkA = physK(c8), pkB = physK(c8 + 4);
    short* AQ = sA[w];
    short* AK = sA[w] + 4096;

    for (int b = blockIdx.x * 2 + w; b < NPB; b += gridDim.x * 2) {
        const int pbase = b * 64;
        #pragma unroll
        for (int it = 0; it < 8; ++it) {
            int p = it * 8 + r8;
            int n = pbase + p;
            short8 qraw = {0,0,0,0,0,0,0,0}, kraw = {0,0,0,0,0,0,0,0};
            if (n < NPTS) {
                qraw = *(const short8*)(QlinH + n * 64 + c8);
                kraw = *(const short8*)(KlinH + n * 64 + c8);
            }
            float qf[8], kf[8];
            #pragma unroll
            for (int e = 0; e < 4; ++e) {
                qf[e]     = fmaxf(fmaf(bf2f((unsigned short)qraw[e]), qa0[e], qb0[e]), 0.f);
                qf[e + 4] = fmaxf(fmaf(bf2f((unsigned short)qraw[e + 4]), qa1[e], qb1[e]), 0.f);
                kf[e]     = fmaxf(fmaf(bf2f((unsigned short)kraw[e]), ka0[e], kb0[e]), 0.f);
                kf[e + 4] = fmaxf(fmaf(bf2f((unsigned short)kraw[e + 4]), ka1[e], kb1[e]), 0.f);
            }
            uint2 qv0 = make_uint2(pk_bf16(qf[0], qf[1]), pk_bf16(qf[2], qf[3]));
            uint2 qv1 = make_uint2(pk_bf16(qf[4], qf[5]), pk_bf16(qf[6], qf[7]));
            uint2 kv0 = make_uint2(pk_bf16(kf[0], kf[1]), pk_bf16(kf[2], kf[3]));
            uint2 kv1 = make_uint2(pk_bf16(kf[4], kf[5]), pk_bf16(kf[6], kf[7]));
            *(uint2*)(AQ + aOff(p, pkA)) = qv0;
            *(uint2*)(AQ + aOff(p, pkB)) = qv1;
            *(uint2*)(AK + aOff(p, pkA)) = kv0;
            *(uint2*)(AK + aOff(p, pkB)) = kv1;
        }
        #pragma unroll
        for (int mt = 0; mt < 4; ++mt) {
            f32x4 aq = (f32x4){0.f, 0.f, 0.f, 0.f};
            f32x4 ak = (f32x4){0.f, 0.f, 0.f, 0.f};
            int r = mt * 16 + g;
            #pragma unroll
            for (int kt = 0; kt < 2; ++kt) {
                int chunk = (kt * 4 + q) ^ (r & 7);
                aq = MFMA16(*(const short8*)(AQ + r * 64 + (chunk << 3)), bimg[kt], aq);
                ak = MFMA16(*(const short8*)(AK + r * 64 + (chunk << 3)), bimg[kt], ak);
            }
            if (g < 8) {
                #pragma unroll
                for (int rg = 0; rg < 4; ++rg) {
                    int n = pbase + mt * 16 + 4 * q + rg;
                    if (n < NPTS) {
                        QW1[n * 8 + g] = aq[rg];
                        KW1[n * 8 + g] = ak[rg];
                    }
                }
            }
        }
    }
}

// ---- W-branch BN stats + W1 materialization (bf16, stats from rounded) ----
__global__ __launch_bounds__(128) void k_wstats(
    const float* __restrict__ coord, const int* __restrict__ ref,
    const float* __restrict__ wp1, const float* __restrict__ bp1,
    const float* __restrict__ bw1e, const float* __restrict__ w2w1,
    const float* __restrict__ QW1, const float* __restrict__ KW1,
    const float* __restrict__ aff, float* __restrict__ stat,
    short* __restrict__ W1H)
{
    __shared__ short sP[2][4096];
    __shared__ float sPos[2][256];
    __shared__ int   sIdx[2][64];
    __shared__ float sRed[16];
    const int tid = threadIdx.x, lane = tid & 63, w = tid >> 6;
    const int q = lane >> 4, g = lane & 15, g7 = lane & 7;
    short8 bimg[2];
    #pragma unroll
    for (int kt = 0; kt < 2; ++kt) {
        short8 bb;
        #pragma unroll
        for (int i = 0; i < 8; ++i) {
            int s = kt * 32 + kib_of(i, q);
            bb[i] = (short)f2bf(g < 8 ? w2w1[s * 8 + g] : 0.f);
        }
        bimg[kt] = bb;
    }
    if (tid < 16) sRed[tid] = 0.f;
    __syncthreads();

    // P1 pair-staging constants: lane owns channels (c2, c2+1), rows rh5..rh5+31
    const int c2 = (lane & 31) * 2, rh5 = (lane >> 5) * 32;
    const float paL = aff[256 + c2],     paH = aff[256 + c2 + 1];
    const float A0L = paL * wp1[c2],       A0H = paH * wp1[c2 + 1];
    const float A1L = paL * wp1[64 + c2],  A1H = paH * wp1[64 + c2 + 1];
    const float A2L = paL * wp1[128 + c2], A2H = paH * wp1[128 + c2 + 1];
    const float B0L = fmaf(paL, bp1[c2], aff[320 + c2]);
    const float B0H = fmaf(paH, bp1[c2 + 1], aff[320 + c2 + 1]);
    const int pOff = physK(c2);
    const float bwg = bw1e[g7];

    short* P = sP[w];
    float* pos = sPos[w];
    int* idxs = sIdx[w];
    float accS = 0.f, accQ = 0.f;

    for (int b = blockIdx.x * 2 + w; b < NBATCH; b += gridDim.x * 2) {
        const int rbase = b * 64;
        const int p0 = b * 4;
        {
            int r = ref[rbase + lane];
            int idx = clip_idx(r);
            idxs[lane] = idx;
            int n = p0 + (lane >> 4);
            pos[lane * 4 + 0] = coord[idx * 3 + 0] - coord[n * 3 + 0];
            pos[lane * 4 + 1] = coord[idx * 3 + 1] - coord[n * 3 + 1];
            pos[lane * 4 + 2] = coord[idx * 3 + 2] - coord[n * 3 + 2];
        }
        // prefetch KW1/QW1 for this batch (latency hides under staging)
        float kwc[16], qwc[4];
        #pragma unroll
        for (int mt = 0; mt < 4; ++mt) {
            int4 i4 = *(const int4*)(idxs + mt * 16 + 4 * q);
            kwc[mt * 4 + 0] = KW1[i4.x * 8 + g7];
            kwc[mt * 4 + 1] = KW1[i4.y * 8 + g7];
            kwc[mt * 4 + 2] = KW1[i4.z * 8 + g7];
            kwc[mt * 4 + 3] = KW1[i4.w * 8 + g7];
            qwc[mt] = QW1[(p0 + mt) * 8 + g7];
        }
        // stage P1 (channel-pair, packed bf16x2 writes)
        #pragma unroll 8
        for (int rr = 0; rr < 32; ++rr) {
            int row = rh5 + rr;
            f32x4 pp = *(const f32x4*)(pos + row * 4);
            float lo = fmaxf(fmaf(pp.x, A0L, fmaf(pp.y, A1L, fmaf(pp.z, A2L, B0L))), 0.f);
            float hi = fmaxf(fmaf(pp.x, A0H, fmaf(pp.y, A1H, fmaf(pp.z, A2H, B0H))), 0.f);
            *(unsigned*)(P + aOff(row, pOff)) = pk_bf16(lo, hi);
        }
        #pragma unroll
        for (int mt = 0; mt < 4; ++mt) {
            f32x4 acc = (f32x4){0.f, 0.f, 0.f, 0.f};
            int r = mt * 16 + g;
            #pragma unroll
            for (int kt = 0; kt < 2; ++kt) {
                int chunk = (kt * 4 + q) ^ (r & 7);
                acc = MFMA16(*(const short8*)(P + r * 64 + (chunk << 3)), bimg[kt], acc);
            }
            if (g < 8) {
                float dq = bwg - qwc[mt];
                #pragma unroll
                for (int rg = 0; rg < 4; ++rg) {
                    float Wf = acc[rg] + kwc[mt * 4 + rg] + dq;
                    unsigned short wh = f2bf(Wf);
                    float Wr = bf2f(wh);
                    accS += Wr;
                    accQ = fmaf(Wr, Wr, accQ);
                    W1H[(rbase + mt * 16 + 4 * q + rg) * 8 + g7] = (short)wh;
                }
            }
        }
    }
    accS += __shfl_xor(accS, 16, 64); accS += __shfl_xor(accS, 32, 64);
    accQ += __shfl_xor(accQ, 16, 64); accQ += __shfl_xor(accQ, 32, 64);
    if (lane < 8) {
        atomicAdd(&sRed[lane], accS);
        atomicAdd(&sRed[8 + lane], accQ);
    }
    __syncthreads();
    if (tid < 16) atomicAdd(&stat[384 + tid], sRed[tid]);
}

// ---- final: W1 -> bn/relu (regs) -> w2 -> softmax; PEB GEMM + einsum ----
// 1-wave blocks (slim LDS); V prefetched into registers, added post-MFMA;
// finB inlined; wn stored bf16 (pitch-10 shorts); exp2-folded softmax.
__global__ __launch_bounds__(64) void k_final(
    const float* __restrict__ coord, const int* __restrict__ ref,
    const float* __restrict__ wp1, const float* __restrict__ bp1,
    const float* __restrict__ wp2,
    const float* __restrict__ ww2, const float* __restrict__ bw2,
    const float* __restrict__ gw_, const float* __restrict__ betaw,
    const short* __restrict__ W1H, const short* __restrict__ VlinH,
    const float* __restrict__ aff, const float* __restrict__ stat,
    float* __restrict__ out)
{
    __shared__ short sP[4096];        // P1 (A-fragment layout), 8 KB
    __shared__ float sPos[256];       // 1 KB
    __shared__ int   sIdx[64];        // 256 B
    __shared__ short sWn[640];        // wn bf16, pitch 10, 1.25 KB
    __shared__ float sW2[72];         // ww2[64]*log2e + bw2[8]*log2e
    const int lane = threadIdx.x;
    const int q = lane >> 4, g15 = lane & 15;
    const float LOG2E = 1.44269504088896340736f;

    sW2[lane] = ww2[lane] * LOG2E;
    if (lane < 8) sW2[64 + lane] = bw2[lane] * LOG2E;
    __syncthreads();

    short8 b1[8];
    #pragma unroll
    for (int tt = 0; tt < 8; ++tt) {
        int kt = tt & 1, nt = tt >> 1;
        short8 bb;
        #pragma unroll
        for (int i = 0; i < 8; ++i) {
            int kk = kt * 32 + kib_of(i, q);
            bb[i] = (short)f2bf(wp2[kk * 64 + nt * 16 + g15]);
        }
        b1[tt] = bb;
    }

    // P1 pair-staging constants
    const int c2 = (lane & 31) * 2, rh5 = (lane >> 5) * 32;
    const float paL = aff[256 + c2],     paH = aff[256 + c2 + 1];
    const float A0L = paL * wp1[c2],       A0H = paH * wp1[c2 + 1];
    const float A1L = paL * wp1[64 + c2],  A1H = paH * wp1[64 + c2 + 1];
    const float A2L = paL * wp1[128 + c2], A2H = paH * wp1[128 + c2 + 1];
    const float B0L = fmaf(paL, bp1[c2], aff[320 + c2]);
    const float B0H = fmaf(paH, bp1[c2 + 1], aff[320 + c2 + 1]);
    const int pOff = physK(c2);
    // finB inline: W-BN affine from stats
    float wa8[8], wb8[8];
    #pragma unroll
    for (int gg = 0; gg < 8; ++gg) {
        const float M = (float)NROW;
        float m = stat[384 + gg] / M;
        float v = stat[392 + gg] / M - m * m;
        float a = gw_[gg] * rsqrtf(v + BN_EPS);
        wa8[gg] = a;
        wb8[gg] = betaw[gg] - m * a;
    }

#define LOADV(MT, VC) do {                                              \
        int4 i4_ = *(const int4*)(sIdx + (MT) * 16 + 4 * q);            \
        int ia_[4] = {i4_.x, i4_.y, i4_.z, i4_.w};                      \
        _Pragma("unroll")                                               \
        for (int rg = 0; rg < 4; ++rg) {                                \
            const short* vb_ = VlinH + ia_[rg] * 64 + g15;              \
            _Pragma("unroll")                                           \
            for (int nt = 0; nt < 4; ++nt)                              \
                VC[rg * 4 + nt] = (unsigned short)vb_[nt * 16];         \
        }                                                               \
    } while (0)

#define EINSUM_MT(MT, VC) do {                                          \
        int r_ = (MT) * 16 + g15;                                       \
        int c0_ = q ^ (r_ & 7);                                         \
        int c1_ = (4 + q) ^ (r_ & 7);                                   \
        short8 a0_ = *(const short8*)(sP + r_ * 64 + (c0_ << 3));       \
        short8 a1_ = *(const short8*)(sP + r_ * 64 + (c1_ << 3));       \
        const int ro0_ = ((MT) * 16 + 4 * q) * 10;                      \
        _Pragma("unroll")                                               \
        for (int nt = 0; nt < 4; ++nt) {                                \
            f32x4 acc_ = (f32x4){0.f, 0.f, 0.f, 0.f};                   \
            acc_ = MFMA16(a0_, b1[nt * 2 + 0], acc_);                   \
            acc_ = MFMA16(a1_, b1[nt * 2 + 1], acc_);                   \
            int col_ = nt * 16 + g15;                                   \
            int o_ = nt * 2 + (g15 >> 3);                               \
            float part_ = 0.f;                                          \
            _Pragma("unroll")                                           \
            for (int rg = 0; rg < 4; ++rg) {                            \
                float v_ = bf2f(VC[rg * 4 + nt]);                       \
                float wn_ = bf2f((unsigned short)sWn[ro0_ + rg * 10 + o_]); \
                part_ = fmaf(v_ + acc_[rg], wn_, part_);                \
            }                                                           \
            part_ += __shfl_xor(part_, 16, 64);                         \
            part_ += __shfl_xor(part_, 32, 64);                         \
            if (q == 0) out[(p0 + (MT)) * 64 + col_] = part_;           \
        }                                                               \
    } while (0)

    for (int b = blockIdx.x; b < NBATCH; b += gridDim.x) {
        const int rbase = b * 64;
        const int p0 = b * 4;
        float maskv;
        {
            int r = ref[rbase + lane];
            int idx = clip_idx(r);
            sIdx[lane] = idx;
            maskv = (r >= 0) ? 1.f : 0.f;
            int n = p0 + (lane >> 4);
            sPos[lane * 4 + 0] = coord[idx * 3 + 0] - coord[n * 3 + 0];
            sPos[lane * 4 + 1] = coord[idx * 3 + 1] - coord[n * 3 + 1];
            sPos[lane * 4 + 2] = coord[idx * 3 + 2] - coord[n * 3 + 2];
        }
        // issue W1 row load early (coalesced; consumed in softmax phase)
        short8 w8 = *(const short8*)(W1H + (rbase + lane) * 8);
        // issue V gathers for mt 0/1 early (consumed only in einsum)
        unsigned short vcA[16], vcB[16], vcC[16], vcD[16];
        LOADV(0, vcA);
        LOADV(1, vcB);
        // stage P1 (channel-pair, packed bf16x2 writes)
        #pragma unroll 8
        for (int rr = 0; rr < 32; ++rr) {
            int row = rh5 + rr;
            f32x4 pp = *(const f32x4*)(sPos + row * 4);
            float lo = fmaxf(fmaf(pp.x, A0L, fmaf(pp.y, A1L, fmaf(pp.z, A2L, B0L))), 0.f);
            float hi = fmaxf(fmaf(pp.x, A0H, fmaf(pp.y, A1H, fmaf(pp.z, A2H, B0H))), 0.f);
            *(unsigned*)(sP + aOff(row, pOff)) = pk_bf16(lo, hi);
        }
        // issue V gathers for mt 2/3
        LOADV(2, vcC);
        LOADV(3, vcD);
        // lane = row: BN+relu on W (regs) + w2 + grouped masked softmax (exp2)
        {
            float h[8];
            #pragma unroll
            for (int gg = 0; gg < 8; ++gg) {
                float Wf = bf2f((unsigned short)w8[gg]);
                h[gg] = fmaxf(fmaf(wa8[gg], Wf, wb8[gg]), 0.f);
            }
            float wv8[8];
            #pragma unroll
            for (int o = 0; o < 8; ++o) {
                float acc = sW2[64 + o];
                #pragma unroll
                for (int gg = 0; gg < 8; ++gg) acc = fmaf(h[gg], sW2[gg * 8 + o], acc);
                float e = exp2f(acc);
                float s = e;
                s += __shfl_xor(s, 1, 64);
                s += __shfl_xor(s, 2, 64);
                s += __shfl_xor(s, 4, 64);
                s += __shfl_xor(s, 8, 64);
                wv8[o] = e * __builtin_amdgcn_rcpf(s) * maskv;
            }
            #pragma unroll
            for (int i = 0; i < 4; ++i)
                *(unsigned*)(sWn + lane * 10 + 2 * i) = pk_bf16(wv8[2 * i], wv8[2 * i + 1]);
        }
        // GEMM1 (PEB) fused with einsum; V fully in registers (post-MFMA add)
        EINSUM_MT(0, vcA);
        EINSUM_MT(1, vcB);
        EINSUM_MT(2, vcC);
        EINSUM_MT(3, vcD);
    }
#undef LOADV
#undef EINSUM_MT
}

extern "C" void kernel_launch(void* const* d_in, const int* in_sizes, int n_in,
                              void* d_out, int out_size, void* d_ws, size_t ws_size,
                              hipStream_t stream)
{
    const float* feat  = (const float*)d_in[0];
    const float* coord = (const float*)d_in[1];
    const int*   ref   = (const int*)d_in[2];
    const float* wq    = (const float*)d_in[3];
    const float* bq    = (const float*)d_in[4];
    const float* gq    = (const float*)d_in[5];
    const float* betaq = (const float*)d_in[6];
    const float* wk    = (const float*)d_in[7];
    const float* bk    = (const float*)d_in[8];
    const float* gk    = (const float*)d_in[9];
    const float* betak = (const float*)d_in[10];
    const float* wv    = (const float*)d_in[11];
    const float* bv    = (const float*)d_in[12];
    const float* wp1   = (const float*)d_in[13];
    const float* bp1   = (const float*)d_in[14];
    const float* gp    = (const float*)d_in[15];
    const float* betap = (const float*)d_in[16];
    const float* wp2   = (const float*)d_in[17];
    const float* bp2   = (const float*)d_in[18];
    const float* ww1   = (const float*)d_in[19];
    const float* bw1   = (const float*)d_in[20];
    const float* gw_   = (const float*)d_in[21];
    const float* betaw = (const float*)d_in[22];
    const float* ww2   = (const float*)d_in[23];
    const float* bw2   = (const float*)d_in[24];

    float* ws    = (float*)d_ws;
    short* QlinH = (short*)(ws + O_QLINH);
    short* KlinH = (short*)(ws + O_KLINH);
    short* VlinH = (short*)(ws + O_VLINH);
    float* stat  = ws + O_STAT;
    float* aff   = ws + O_AFF;
    float* w2w1  = ws + O_W2W1;
    float* bw1e  = ws + O_BW1E;
    float* QW1   = ws + O_QW1;
    float* KW1   = ws + O_KW1;
    short* W1H   = (short*)(ws + O_W1H);
    float* out   = (float*)d_out;

    hipLaunchKernelGGL(k_prep, dim3(1), dim3(512), 0, stream,
                       wp2, ww1, bw1, bp2, stat, w2w1, bw1e);
    hipLaunchKernelGGL(k_qkv, dim3(QKV_BLOCKS + 128), dim3(256), 0, stream,
                       feat, wq, bq, wk, bk, wv, bv, bp2, coord, ref,
                       QlinH, KlinH, VlinH, stat);
    hipLaunchKernelGGL(k_finA, dim3(1), dim3(192), 0, stream,
                       gq, betaq, gk, betak, gp, betap, wp1, bp1, stat, aff);
    hipLaunchKernelGGL(k_qkw, dim3(782), dim3(128), 0, stream,
                       QlinH, KlinH, ww1, aff, QW1, KW1);
    hipLaunchKernelGGL(k_wstats, dim3(5000), dim3(128), 0, stream,
                       coord, ref, wp1, bp1, bw1e, w2w1, QW1, KW1, aff, stat, W1H);
    hipLaunchKernelGGL(k_final, dim3(6250), dim3(64), 0, stream,
                       coord, ref, wp1, bp1, wp2, ww2, bw2, gw_, betaw,
                       W1H, VlinH, aff, stat, out);
}

// Round 15
// 212.649 us; speedup vs baseline: 1.0976x; 1.0976x over previous
//
#include <hip/hip_runtime.h>
#include <hip/hip_bf16.h>

#define NPTS 100000
#define KNBR 16
#define CCH  64
#define GRP  8
#define BN_EPS 1e-5f
#define NROW (NPTS * KNBR)        // 1,600,000
#define NBATCH (NROW / 64)        // 25,000 batches of 64 rows (4 points)
#define NPB   ((NPTS + 63) / 64)  // 1563 point-batches

// ---- workspace layout (float offsets) ----
#define O_QLINH 0                  // NPTS*64 bf16 = NPTS*32 floats
#define O_KLINH (NPTS * 32)
#define O_VLINH (NPTS * 64)
#define O_STAT  (NPTS * 96)        // 416 floats of stats
#define O_AFF   (O_STAT + 416)     // 416 floats of affines
#define O_W2W1  (O_AFF + 416)      // 512 floats: wp2@ww1 [64][8]
#define O_BW1E  (O_W2W1 + 512)     // 8 floats: bw1 + bp2@ww1
#define O_QW1   (O_BW1E + 8)       // NPTS*8 fp32
#define O_KW1   (O_QW1 + NPTS * 8) // NPTS*8 fp32
#define O_W1H   (O_KW1 + NPTS * 8) // NROW*8 bf16 = NROW*4 floats (25.6 MB)

typedef __attribute__((ext_vector_type(8))) short short8;
typedef __attribute__((ext_vector_type(4))) short short4v;
typedef __attribute__((ext_vector_type(4))) float f32x4;
#define MFMA16(a, b, c) __builtin_amdgcn_mfma_f32_16x16x32_bf16(a, b, c, 0, 0, 0)

__device__ __forceinline__ int clip_idx(int r) {
    int i = r < 0 ? 0 : r;
    return i >= NPTS ? NPTS - 1 : i;
}
__device__ __forceinline__ unsigned short f2bf(float x) {
    union { float f; unsigned u; } v; v.f = x;
    unsigned r = v.u + 0x7fffu + ((v.u >> 16) & 1u);
    return (unsigned short)(r >> 16);
}
__device__ __forceinline__ float bf2f(unsigned short h) {
    union { unsigned u; float f; } v; v.u = ((unsigned)h) << 16;
    return v.f;
}
// packed f32x2 -> bf16x2 (single HW instruction; no builtin on gfx950)
__device__ __forceinline__ unsigned pk_bf16(float lo, float hi) {
    unsigned r;
    asm("v_cvt_pk_bf16_f32 %0, %1, %2" : "=v"(r) : "v"(lo), "v"(hi));
    return r;
}
// K-slot s -> physical short offset within a row (A-fragment-linear order)
__device__ __forceinline__ int physK(int s) {
    return (s >> 5) * 32 + ((s >> 2) & 3) * 8 + ((s >> 4) & 1) * 4 + (s & 3);
}
// short index into a [64 rows][64 K-slots] A-buffer with 16B-chunk XOR swizzle
__device__ __forceinline__ int aOff(int r, int p) {
    return r * 64 + (((p >> 3) ^ (r & 7)) << 3) + (p & 7);
}
// element i of a B fragment for quarter q: K-in-block index
__device__ __forceinline__ int kib_of(int i, int q) {
    return (i < 4) ? (4 * q + i) : (16 + 4 * q + (i - 4));
}

// ---- prep: zero stats + w2w1 = wp2@ww1 + bw1e = bw1 + bp2@ww1 ----
__global__ __launch_bounds__(512) void k_prep(
    const float* __restrict__ wp2, const float* __restrict__ ww1,
    const float* __restrict__ bw1, const float* __restrict__ bp2,
    float* __restrict__ stat, float* __restrict__ w2w1, float* __restrict__ bw1e)
{
    int t = threadIdx.x;
    if (t < 416) stat[t] = 0.f;
    int j = t >> 3, g = t & 7;
    float acc = 0.f;
    #pragma unroll 16
    for (int c = 0; c < 64; ++c) acc = fmaf(wp2[j * 64 + c], ww1[c * 8 + g], acc);
    w2w1[t] = acc;
    if (t < 8) {
        float b = bw1[t];
        #pragma unroll 16
        for (int c = 0; c < 64; ++c) b = fmaf(bp2[c], ww1[c * 8 + t], b);
        bw1e[t] = b;
    }
}

// ---- Q/K/V projection via MFMA + Q/K BN stats; pmom fused as extra blocks ----
// Wave w owns col-tile w of EACH of Q,K,V (branch-free epilogue).
// V gets bp2 folded in (einsum adds V+PEB+bp2).
#define QKV_BLOCKS 512
__global__ __launch_bounds__(256) void k_qkv(
    const float* __restrict__ feat,
    const float* __restrict__ wq, const float* __restrict__ bq,
    const float* __restrict__ wk, const float* __restrict__ bk,
    const float* __restrict__ wv, const float* __restrict__ bv,
    const float* __restrict__ bp2,
    const float* __restrict__ coord, const int* __restrict__ ref,
    short* __restrict__ QlinH, short* __restrict__ KlinH, short* __restrict__ VlinH,
    float* __restrict__ stat)
{
    __shared__ short sA[4096];
    __shared__ float s_red[9];
    const int tid = threadIdx.x, lane = tid & 63, w = tid >> 6;
    const int q = lane >> 4, c15 = lane & 15;

    if (blockIdx.x >= QKV_BLOCKS) {
        // ---- pmom body ----
        float m[9];
        #pragma unroll
        for (int i = 0; i < 9; ++i) m[i] = 0.f;
        const int gid = (blockIdx.x - QKV_BLOCKS) * 256 + tid;
        const int stride = 128 * 256;
        for (int row = gid; row < NROW; row += stride) {
            int n = row >> 4;
            int idx = clip_idx(ref[row]);
            float px = coord[idx * 3 + 0] - coord[n * 3 + 0];
            float py = coord[idx * 3 + 1] - coord[n * 3 + 1];
            float pz = coord[idx * 3 + 2] - coord[n * 3 + 2];
            m[0] += px; m[1] += py; m[2] += pz;
            m[3] = fmaf(px, px, m[3]); m[4] = fmaf(py, py, m[4]); m[5] = fmaf(pz, pz, m[5]);
            m[6] = fmaf(px, py, m[6]); m[7] = fmaf(px, pz, m[7]); m[8] = fmaf(py, pz, m[8]);
        }
        if (tid < 9) s_red[tid] = 0.f;
        __syncthreads();
        #pragma unroll
        for (int off = 32; off >= 1; off >>= 1) {
            #pragma unroll
            for (int i = 0; i < 9; ++i) m[i] += __shfl_xor(m[i], off, 64);
        }
        if (lane == 0) {
            #pragma unroll
            for (int i = 0; i < 9; ++i) atomicAdd(&s_red[i], m[i]);
        }
        __syncthreads();
        if (tid < 9) atomicAdd(&stat[256 + tid], s_red[tid]);
        return;
    }

    // B fragments + bias: wave w owns col-tile w of wq, wk, wv
    const int colg = w * 16 + c15;
    short8 bfrag[3][2];
    float bias[3];
    {
        const float* Ws[3] = {wq, wk, wv};
        bias[0] = bq[colg];
        bias[1] = bk[colg];
        bias[2] = bv[colg] + bp2[colg];
        #pragma unroll
        for (int t = 0; t < 3; ++t) {
            #pragma unroll
            for (int kt = 0; kt < 2; ++kt) {
                short8 bb;
                #pragma unroll
                for (int i = 0; i < 8; ++i) {
                    int kk = kt * 32 + kib_of(i, q);
                    bb[i] = (short)f2bf(Ws[t][kk * 64 + colg]);
                }
                bfrag[t][kt] = bb;
            }
        }
    }
    float qs = 0.f, qs2 = 0.f, ks = 0.f, ks2 = 0.f;

    const int c4 = c15 * 4;              // 4-channel group
    const int pk4 = physK(c4);           // contiguous 4 slots

    for (int b = blockIdx.x; b < NPB; b += QKV_BLOCKS) {
        const int pbase = b * 64;
        // staging: float4 loads, 4 rows per instr
        #pragma unroll
        for (int i = 0; i < 4; ++i) {
            int p = w * 16 + i * 4 + q;
            int n = pbase + p;
            float4 v = make_float4(0.f, 0.f, 0.f, 0.f);
            if (n < NPTS) v = *(const float4*)(feat + n * 64 + c4);
            short4v h;
            h[0] = (short)f2bf(v.x); h[1] = (short)f2bf(v.y);
            h[2] = (short)f2bf(v.z); h[3] = (short)f2bf(v.w);
            *(short4v*)(sA + aOff(p, pk4)) = h;
        }
        __syncthreads();
        #pragma unroll
        for (int mt = 0; mt < 4; ++mt) {
            int r = mt * 16 + c15;
            int ch0 = q ^ (r & 7);
            int ch1 = (4 + q) ^ (r & 7);
            short8 a0 = *(const short8*)(sA + r * 64 + (ch0 << 3));
            short8 a1 = *(const short8*)(sA + r * 64 + (ch1 << 3));
            #pragma unroll
            for (int t = 0; t < 3; ++t) {
                f32x4 acc = (f32x4){0.f, 0.f, 0.f, 0.f};
                acc = MFMA16(a0, bfrag[t][0], acc);
                acc = MFMA16(a1, bfrag[t][1], acc);
                #pragma unroll
                for (int rg = 0; rg < 4; ++rg) {
                    int row = mt * 16 + 4 * q + rg;
                    int n = pbase + row;
                    if (n < NPTS) {
                        unsigned short h = f2bf(acc[rg] + bias[t]);
                        if (t == 0) {
                            QlinH[n * 64 + colg] = (short)h;
                            float vr = bf2f(h);
                            qs += vr; qs2 = fmaf(vr, vr, qs2);
                        } else if (t == 1) {
                            KlinH[n * 64 + colg] = (short)h;
                            float vr = bf2f(h);
                            ks += vr; ks2 = fmaf(vr, vr, ks2);
                        } else {
                            VlinH[n * 64 + colg] = (short)h;
                        }
                    }
                }
            }
        }
        __syncthreads();
    }
    qs += __shfl_xor(qs, 16, 64);  qs += __shfl_xor(qs, 32, 64);
    qs2 += __shfl_xor(qs2, 16, 64); qs2 += __shfl_xor(qs2, 32, 64);
    ks += __shfl_xor(ks, 16, 64);  ks += __shfl_xor(ks, 32, 64);
    ks2 += __shfl_xor(ks2, 16, 64); ks2 += __shfl_xor(ks2, 32, 64);
    if (q == 0) {
        atomicAdd(&stat[colg], qs);
        atomicAdd(&stat[64 + colg], qs2);
        atomicAdd(&stat[128 + colg], ks);
        atomicAdd(&stat[192 + colg], ks2);
    }
}

// ---- finalize q/k/p BN affines ----
__global__ __launch_bounds__(192) void k_finA(
    const float* __restrict__ gq, const float* __restrict__ betaq,
    const float* __restrict__ gk, const float* __restrict__ betak,
    const float* __restrict__ gp, const float* __restrict__ betap,
    const float* __restrict__ wp1, const float* __restrict__ bp1,
    const float* __restrict__ stat, float* __restrict__ aff)
{
    int t = threadIdx.x;
    if (t < 64) {
        float m = stat[t] / (float)NPTS;
        float v = stat[64 + t] / (float)NPTS - m * m;
        float a = gq[t] * rsqrtf(v + BN_EPS);
        aff[t] = a;
        aff[64 + t] = betaq[t] - m * a;
    } else if (t < 128) {
        int c = t - 64;
        float m = stat[128 + c] / (float)NPTS;
        float v = stat[192 + c] / (float)NPTS - m * m;
        float a = gk[c] * rsqrtf(v + BN_EPS);
        aff[128 + c] = a;
        aff[192 + c] = betak[c] - m * a;
    } else {
        int c = t - 128;
        const float R = (float)NROW;
        float Ex = stat[256] / R, Ey = stat[257] / R, Ez = stat[258] / R;
        float Exx = stat[259] / R, Eyy = stat[260] / R, Ezz = stat[261] / R;
        float Exy = stat[262] / R, Exz = stat[263] / R, Eyz = stat[264] / R;
        float Cxx = Exx - Ex * Ex, Cyy = Eyy - Ey * Ey, Czz = Ezz - Ez * Ez;
        float Cxy = Exy - Ex * Ey, Cxz = Exz - Ex * Ez, Cyz = Eyz - Ey * Ez;
        float a0 = wp1[c], a1 = wp1[64 + c], a2 = wp1[128 + c];
        float mean = a0 * Ex + a1 * Ey + a2 * Ez + bp1[c];
        float var = a0 * a0 * Cxx + a1 * a1 * Cyy + a2 * a2 * Czz
                  + 2.f * (a0 * a1 * Cxy + a0 * a2 * Cxz + a1 * a2 * Cyz);
        float a = gp[c] * rsqrtf(var + BN_EPS);
        aff[256 + c] = a;
        aff[320 + c] = betap[c] - mean * a;
    }
}

// ---- per-point QW1/KW1 = relu_bn(Q/K) @ ww1 via MFMA ----
__global__ __launch_bounds__(128) void k_qkw(
    const short* __restrict__ QlinH, const short* __restrict__ KlinH,
    const float* __restrict__ ww1, const float* __restrict__ aff,
    float* __restrict__ QW1, float* __restrict__ KW1)
{
    __shared__ short sA[2][8192];
    const int tid = threadIdx.x, lane = tid & 63, w = tid >> 6;
    const int q = lane >> 4, g = lane & 15;
    short8 bimg[2];
    #pragma unroll
    for (int kt = 0; kt < 2; ++kt) {
        short8 bb;
        #pragma unroll
        for (int i = 0; i < 8; ++i) {
            int s = kt * 32 + kib_of(i, q);
            bb[i] = (short)f2bf(g < 8 ? ww1[s * 8 + g] : 0.f);
        }
        bimg[kt] = bb;
    }
    // staging coeffs: lane handles 8 channels c8..c8+7 of 8 rows
    const int r8 = lane >> 3, c8 = (lane & 7) * 8;
    f32x4 qa0 = *(const f32x4*)(aff + c8),       qa1 = *(const f32x4*)(aff + c8 + 4);
    f32x4 qb0 = *(const f32x4*)(aff + 64 + c8),  qb1 = *(const f32x4*)(aff + 64 + c8 + 4);
    f32x4 ka0 = *(const f32x4*)(aff + 128 + c8), ka1 = *(const f32x4*)(aff + 128 + c8 + 4);
    f32x4 kb0 = *(const f32x4*)(aff + 192 + c8), kb1 = *(const f32x4*)(aff + 192 + c8 + 4);
    const int pkA = physK(c8), pkB = physK(c8 + 4);
    short* AQ = sA[w];
    short* AK = sA[w] + 4096;

    for (int b = blockIdx.x * 2 + w; b < NPB; b += gridDim.x * 2) {
        const int pbase = b * 64;
        #pragma unroll
        for (int it = 0; it < 8; ++it) {
            int p = it * 8 + r8;
            int n = pbase + p;
            short8 qraw = {0,0,0,0,0,0,0,0}, kraw = {0,0,0,0,0,0,0,0};
            if (n < NPTS) {
                qraw = *(const short8*)(QlinH + n * 64 + c8);
                kraw = *(const short8*)(KlinH + n * 64 + c8);
            }
            float qf[8], kf[8];
            #pragma unroll
            for (int e = 0; e < 4; ++e) {
                qf[e]     = fmaxf(fmaf(bf2f((unsigned short)qraw[e]), qa0[e], qb0[e]), 0.f);
                qf[e + 4] = fmaxf(fmaf(bf2f((unsigned short)qraw[e + 4]), qa1[e], qb1[e]), 0.f);
                kf[e]     = fmaxf(fmaf(bf2f((unsigned short)kraw[e]), ka0[e], kb0[e]), 0.f);
                kf[e + 4] = fmaxf(fmaf(bf2f((unsigned short)kraw[e + 4]), ka1[e], kb1[e]), 0.f);
            }
            uint2 qv0 = make_uint2(pk_bf16(qf[0], qf[1]), pk_bf16(qf[2], qf[3]));
            uint2 qv1 = make_uint2(pk_bf16(qf[4], qf[5]), pk_bf16(qf[6], qf[7]));
            uint2 kv0 = make_uint2(pk_bf16(kf[0], kf[1]), pk_bf16(kf[2], kf[3]));
            uint2 kv1 = make_uint2(pk_bf16(kf[4], kf[5]), pk_bf16(kf[6], kf[7]));
            *(uint2*)(AQ + aOff(p, pkA)) = qv0;
            *(uint2*)(AQ + aOff(p, pkB)) = qv1;
            *(uint2*)(AK + aOff(p, pkA)) = kv0;
            *(uint2*)(AK + aOff(p, pkB)) = kv1;
        }
        #pragma unroll
        for (int mt = 0; mt < 4; ++mt) {
            f32x4 aq = (f32x4){0.f, 0.f, 0.f, 0.f};
            f32x4 ak = (f32x4){0.f, 0.f, 0.f, 0.f};
            int r = mt * 16 + g;
            #pragma unroll
            for (int kt = 0; kt < 2; ++kt) {
                int chunk = (kt * 4 + q) ^ (r & 7);
                aq = MFMA16(*(const short8*)(AQ + r * 64 + (chunk << 3)), bimg[kt], aq);
                ak = MFMA16(*(const short8*)(AK + r * 64 + (chunk << 3)), bimg[kt], ak);
            }
            if (g < 8) {
                #pragma unroll
                for (int rg = 0; rg < 4; ++rg) {
                    int n = pbase + mt * 16 + 4 * q + rg;
                    if (n < NPTS) {
                        QW1[n * 8 + g] = aq[rg];
                        KW1[n * 8 + g] = ak[rg];
                    }
                }
            }
        }
    }
}

// ---- W-branch BN stats + W1 materialization (bf16, stats from rounded) ----
__global__ __launch_bounds__(128) void k_wstats(
    const float* __restrict__ coord, const int* __restrict__ ref,
    const float* __restrict__ wp1, const float* __restrict__ bp1,
    const float* __restrict__ bw1e, const float* __restrict__ w2w1,
    const float* __restrict__ QW1, const float* __restrict__ KW1,
    const float* __restrict__ aff, float* __restrict__ stat,
    short* __restrict__ W1H)
{
    __shared__ short sP[2][4096];
    __shared__ float sPos[2][256];
    __shared__ int   sIdx[2][64];
    __shared__ float sRed[16];
    const int tid = threadIdx.x, lane = tid & 63, w = tid >> 6;
    const int q = lane >> 4, g = lane & 15, g7 = lane & 7;
    short8 bimg[2];
    #pragma unroll
    for (int kt = 0; kt < 2; ++kt) {
        short8 bb;
        #pragma unroll
        for (int i = 0; i < 8; ++i) {
            int s = kt * 32 + kib_of(i, q);
            bb[i] = (short)f2bf(g < 8 ? w2w1[s * 8 + g] : 0.f);
        }
        bimg[kt] = bb;
    }
    if (tid < 16) sRed[tid] = 0.f;
    __syncthreads();

    // P1 pair-staging constants: lane owns channels (c2, c2+1), rows rh5..rh5+31
    const int c2 = (lane & 31) * 2, rh5 = (lane >> 5) * 32;
    const float paL = aff[256 + c2],     paH = aff[256 + c2 + 1];
    const float A0L = paL * wp1[c2],       A0H = paH * wp1[c2 + 1];
    const float A1L = paL * wp1[64 + c2],  A1H = paH * wp1[64 + c2 + 1];
    const float A2L = paL * wp1[128 + c2], A2H = paH * wp1[128 + c2 + 1];
    const float B0L = fmaf(paL, bp1[c2], aff[320 + c2]);
    const float B0H = fmaf(paH, bp1[c2 + 1], aff[320 + c2 + 1]);
    const int pOff = physK(c2);
    const float bwg = bw1e[g7];

    short* P = sP[w];
    float* pos = sPos[w];
    int* idxs = sIdx[w];
    float accS = 0.f, accQ = 0.f;

    for (int b = blockIdx.x * 2 + w; b < NBATCH; b += gridDim.x * 2) {
        const int rbase = b * 64;
        const int p0 = b * 4;
        {
            int r = ref[rbase + lane];
            int idx = clip_idx(r);
            idxs[lane] = idx;
            int n = p0 + (lane >> 4);
            pos[lane * 4 + 0] = coord[idx * 3 + 0] - coord[n * 3 + 0];
            pos[lane * 4 + 1] = coord[idx * 3 + 1] - coord[n * 3 + 1];
            pos[lane * 4 + 2] = coord[idx * 3 + 2] - coord[n * 3 + 2];
        }
        // prefetch KW1/QW1 for this batch (latency hides under staging)
        float kwc[16], qwc[4];
        #pragma unroll
        for (int mt = 0; mt < 4; ++mt) {
            int4 i4 = *(const int4*)(idxs + mt * 16 + 4 * q);
            kwc[mt * 4 + 0] = KW1[i4.x * 8 + g7];
            kwc[mt * 4 + 1] = KW1[i4.y * 8 + g7];
            kwc[mt * 4 + 2] = KW1[i4.z * 8 + g7];
            kwc[mt * 4 + 3] = KW1[i4.w * 8 + g7];
            qwc[mt] = QW1[(p0 + mt) * 8 + g7];
        }
        // stage P1 (channel-pair, packed bf16x2 writes)
        #pragma unroll 8
        for (int rr = 0; rr < 32; ++rr) {
            int row = rh5 + rr;
            f32x4 pp = *(const f32x4*)(pos + row * 4);
            float lo = fmaxf(fmaf(pp.x, A0L, fmaf(pp.y, A1L, fmaf(pp.z, A2L, B0L))), 0.f);
            float hi = fmaxf(fmaf(pp.x, A0H, fmaf(pp.y, A1H, fmaf(pp.z, A2H, B0H))), 0.f);
            *(unsigned*)(P + aOff(row, pOff)) = pk_bf16(lo, hi);
        }
        #pragma unroll
        for (int mt = 0; mt < 4; ++mt) {
            f32x4 acc = (f32x4){0.f, 0.f, 0.f, 0.f};
            int r = mt * 16 + g;
            #pragma unroll
            for (int kt = 0; kt < 2; ++kt) {
                int chunk = (kt * 4 + q) ^ (r & 7);
                acc = MFMA16(*(const short8*)(P + r * 64 + (chunk << 3)), bimg[kt], acc);
            }
            if (g < 8) {
                float dq = bwg - qwc[mt];
                #pragma unroll
                for (int rg = 0; rg < 4; ++rg) {
                    float Wf = acc[rg] + kwc[mt * 4 + rg] + dq;
                    unsigned short wh = f2bf(Wf);
                    float Wr = bf2f(wh);
                    accS += Wr;
                    accQ = fmaf(Wr, Wr, accQ);
                    W1H[(rbase + mt * 16 + 4 * q + rg) * 8 + g7] = (short)wh;
                }
            }
        }
    }
    accS += __shfl_xor(accS, 16, 64); accS += __shfl_xor(accS, 32, 64);
    accQ += __shfl_xor(accQ, 16, 64); accQ += __shfl_xor(accQ, 32, 64);
    if (lane < 8) {
        atomicAdd(&sRed[lane], accS);
        atomicAdd(&sRed[8 + lane], accQ);
    }
    __syncthreads();
    if (tid < 16) atomicAdd(&stat[384 + tid], sRed[tid]);
}

// ---- final: W1 -> bn/relu (regs) -> w2 -> softmax; PEB GEMM + einsum ----
// 1-wave blocks (slim LDS => high occupancy); V prefetched into registers;
// finB inlined; wn stored bf16 (pitch-10 shorts).
__global__ __launch_bounds__(64) void k_final(
    const float* __restrict__ coord, const int* __restrict__ ref,
    const float* __restrict__ wp1, const float* __restrict__ bp1,
    const float* __restrict__ wp2,
    const float* __restrict__ ww2, const float* __restrict__ bw2,
    const float* __restrict__ gw_, const float* __restrict__ betaw,
    const short* __restrict__ W1H, const short* __restrict__ VlinH,
    const float* __restrict__ aff, const float* __restrict__ stat,
    float* __restrict__ out)
{
    __shared__ short sP[4096];        // P1 (A-fragment layout), 8 KB
    __shared__ float sPos[256];       // 1 KB
    __shared__ int   sIdx[64];        // 256 B
    __shared__ short sWn[640];        // wn bf16, pitch 10, 1.25 KB
    __shared__ float sW2[72];         // ww2[64] + bw2[8]
    const int lane = threadIdx.x;
    const int q = lane >> 4, g15 = lane & 15;

    sW2[lane] = ww2[lane];
    if (lane < 8) sW2[64 + lane] = bw2[lane];
    __syncthreads();

    short8 b1[8];
    #pragma unroll
    for (int tt = 0; tt < 8; ++tt) {
        int kt = tt & 1, nt = tt >> 1;
        short8 bb;
        #pragma unroll
        for (int i = 0; i < 8; ++i) {
            int kk = kt * 32 + kib_of(i, q);
            bb[i] = (short)f2bf(wp2[kk * 64 + nt * 16 + g15]);
        }
        b1[tt] = bb;
    }

    // P1 pair-staging constants
    const int c2 = (lane & 31) * 2, rh5 = (lane >> 5) * 32;
    const float paL = aff[256 + c2],     paH = aff[256 + c2 + 1];
    const float A0L = paL * wp1[c2],       A0H = paH * wp1[c2 + 1];
    const float A1L = paL * wp1[64 + c2],  A1H = paH * wp1[64 + c2 + 1];
    const float A2L = paL * wp1[128 + c2], A2H = paH * wp1[128 + c2 + 1];
    const float B0L = fmaf(paL, bp1[c2], aff[320 + c2]);
    const float B0H = fmaf(paH, bp1[c2 + 1], aff[320 + c2 + 1]);
    const int pOff = physK(c2);
    // finB inline: W-BN affine from stats
    float wa8[8], wb8[8];
    #pragma unroll
    for (int gg = 0; gg < 8; ++gg) {
        const float M = (float)NROW;
        float m = stat[384 + gg] / M;
        float v = stat[392 + gg] / M - m * m;
        float a = gw_[gg] * rsqrtf(v + BN_EPS);
        wa8[gg] = a;
        wb8[gg] = betaw[gg] - m * a;
    }

#define LOADV(MT, VC) do {                                              \
        int4 i4_ = *(const int4*)(sIdx + (MT) * 16 + 4 * q);            \
        int ia_[4] = {i4_.x, i4_.y, i4_.z, i4_.w};                      \
        _Pragma("unroll")                                               \
        for (int rg = 0; rg < 4; ++rg) {                                \
            const short* vb_ = VlinH + ia_[rg] * 64 + g15;              \
            _Pragma("unroll")                                           \
            for (int nt = 0; nt < 4; ++nt)                              \
                VC[rg * 4 + nt] = (unsigned short)vb_[nt * 16];         \
        }                                                               \
    } while (0)

#define EINSUM_MT(MT, VC) do {                                          \
        int r_ = (MT) * 16 + g15;                                       \
        int c0_ = q ^ (r_ & 7);                                         \
        int c1_ = (4 + q) ^ (r_ & 7);                                   \
        short8 a0_ = *(const short8*)(sP + r_ * 64 + (c0_ << 3));       \
        short8 a1_ = *(const short8*)(sP + r_ * 64 + (c1_ << 3));       \
        const int ro0_ = ((MT) * 16 + 4 * q) * 10;                      \
        _Pragma("unroll")                                               \
        for (int nt = 0; nt < 4; ++nt) {                                \
            f32x4 acc_ = (f32x4){0.f, 0.f, 0.f, 0.f};                   \
            acc_ = MFMA16(a0_, b1[nt * 2 + 0], acc_);                   \
            acc_ = MFMA16(a1_, b1[nt * 2 + 1], acc_);                   \
            int col_ = nt * 16 + g15;                                   \
            int o_ = nt * 2 + (g15 >> 3);                               \
            float part_ = 0.f;                                          \
            _Pragma("unroll")                                           \
            for (int rg = 0; rg < 4; ++rg) {                            \
                float v_ = bf2f(VC[rg * 4 + nt]);                       \
                float wn_ = bf2f((unsigned short)sWn[ro0_ + rg * 10 + o_]); \
                part_ = fmaf(v_ + acc_[rg], wn_, part_);                \
            }                                                           \
            part_ += __shfl_xor(part_, 16, 64);                         \
            part_ += __shfl_xor(part_, 32, 64);                         \
            if (q == 0) out[(p0 + (MT)) * 64 + col_] = part_;           \
        }                                                               \
    } while (0)

    for (int b = blockIdx.x; b < NBATCH; b += gridDim.x) {
        const int rbase = b * 64;
        const int p0 = b * 4;
        float maskv;
        {
            int r = ref[rbase + lane];
            int idx = clip_idx(r);
            sIdx[lane] = idx;
            maskv = (r >= 0) ? 1.f : 0.f;
            int n = p0 + (lane >> 4);
            sPos[lane * 4 + 0] = coord[idx * 3 + 0] - coord[n * 3 + 0];
            sPos[lane * 4 + 1] = coord[idx * 3 + 1] - coord[n * 3 + 1];
            sPos[lane * 4 + 2] = coord[idx * 3 + 2] - coord[n * 3 + 2];
        }
        // issue W1 row load early (coalesced; consumed in softmax phase)
        short8 w8 = *(const short8*)(W1H + (rbase + lane) * 8);
        // issue V gathers for mt 0/1 early (consumed only in einsum)
        unsigned short vcA[16], vcB[16], vcC[16], vcD[16];
        LOADV(0, vcA);
        LOADV(1, vcB);
        // stage P1 (channel-pair, packed bf16x2 writes)
        #pragma unroll 8
        for (int rr = 0; rr < 32; ++rr) {
            int row = rh5 + rr;
            f32x4 pp = *(const f32x4*)(sPos + row * 4);
            float lo = fmaxf(fmaf(pp.x, A0L, fmaf(pp.y, A1L, fmaf(pp.z, A2L, B0L))), 0.f);
            float hi = fmaxf(fmaf(pp.x, A0H, fmaf(pp.y, A1H, fmaf(pp.z, A2H, B0H))), 0.f);
            *(unsigned*)(sP + aOff(row, pOff)) = pk_bf16(lo, hi);
        }
        // issue V gathers for mt 2/3
        LOADV(2, vcC);
        LOADV(3, vcD);
        // lane = row: BN+relu on W (regs) + w2 + grouped masked softmax
        {
            float h[8];
            #pragma unroll
            for (int gg = 0; gg < 8; ++gg) {
                float Wf = bf2f((unsigned short)w8[gg]);
                h[gg] = fmaxf(fmaf(wa8[gg], Wf, wb8[gg]), 0.f);
            }
            float wv8[8];
            #pragma unroll
            for (int o = 0; o < 8; ++o) {
                float acc = sW2[64 + o];
                #pragma unroll
                for (int gg = 0; gg < 8; ++gg) acc = fmaf(h[gg], sW2[gg * 8 + o], acc);
                float e = __expf(acc);
                float s = e;
                s += __shfl_xor(s, 1, 64);
                s += __shfl_xor(s, 2, 64);
                s += __shfl_xor(s, 4, 64);
                s += __shfl_xor(s, 8, 64);
                wv8[o] = e * __builtin_amdgcn_rcpf(s) * maskv;
            }
            #pragma unroll
            for (int i = 0; i < 4; ++i)
                *(unsigned*)(sWn + lane * 10 + 2 * i) = pk_bf16(wv8[2 * i], wv8[2 * i + 1]);
        }
        // GEMM1 (PEB) fused with einsum; V fully in registers
        EINSUM_MT(0, vcA);
        EINSUM_MT(1, vcB);
        EINSUM_MT(2, vcC);
        EINSUM_MT(3, vcD);
    }
#undef LOADV
#undef EINSUM_MT
}

extern "C" void kernel_launch(void* const* d_in, const int* in_sizes, int n_in,
                              void* d_out, int out_size, void* d_ws, size_t ws_size,
                              hipStream_t stream)
{
    const float* feat  = (const float*)d_in[0];
    const float* coord = (const float*)d_in[1];
    const int*   ref   = (const int*)d_in[2];
    const float* wq    = (const float*)d_in[3];
    const float* bq    = (const float*)d_in[4];
    const float* gq    = (const float*)d_in[5];
    const float* betaq = (const float*)d_in[6];
    const float* wk    = (const float*)d_in[7];
    const float* bk    = (const float*)d_in[8];
    const float* gk    = (const float*)d_in[9];
    const float* betak = (const float*)d_in[10];
    const float* wv    = (const float*)d_in[11];
    const float* bv    = (const float*)d_in[12];
    const float* wp1   = (const float*)d_in[13];
    const float* bp1   = (const float*)d_in[14];
    const float* gp    = (const float*)d_in[15];
    const float* betap = (const float*)d_in[16];
    const float* wp2   = (const float*)d_in[17];
    const float* bp2   = (const float*)d_in[18];
    const float* ww1   = (const float*)d_in[19];
    const float* bw1   = (const float*)d_in[20];
    const float* gw_   = (const float*)d_in[21];
    const float* betaw = (const float*)d_in[22];
    const float* ww2   = (const float*)d_in[23];
    const float* bw2   = (const float*)d_in[24];

    float* ws    = (float*)d_ws;
    short* QlinH = (short*)(ws + O_QLINH);
    short* KlinH = (short*)(ws + O_KLINH);
    short* VlinH = (short*)(ws + O_VLINH);
    float* stat  = ws + O_STAT;
    float* aff   = ws + O_AFF;
    float* w2w1  = ws + O_W2W1;
    float* bw1e  = ws + O_BW1E;
    float* QW1   = ws + O_QW1;
    float* KW1   = ws + O_KW1;
    short* W1H   = (short*)(ws + O_W1H);
    float* out   = (float*)d_out;

    hipLaunchKernelGGL(k_prep, dim3(1), dim3(512), 0, stream,
                       wp2, ww1, bw1, bp2, stat, w2w1, bw1e);
    hipLaunchKernelGGL(k_qkv, dim3(QKV_BLOCKS + 128), dim3(256), 0, stream,
                       feat, wq, bq, wk, bk, wv, bv, bp2, coord, ref,
                       QlinH, KlinH, VlinH, stat);
    hipLaunchKernelGGL(k_finA, dim3(1), dim3(192), 0, stream,
                       gq, betaq, gk, betak, gp, betap, wp1, bp1, stat, aff);
    hipLaunchKernelGGL(k_qkw, dim3(782), dim3(128), 0, stream,
                       QlinH, KlinH, ww1, aff, QW1, KW1);
    hipLaunchKernelGGL(k_wstats, dim3(2500), dim3(128), 0, stream,
                       coord, ref, wp1, bp1, bw1e, w2w1, QW1, KW1, aff, stat, W1H);
    hipLaunchKernelGGL(k_final, dim3(6250), dim3(64), 0, stream,
                       coord, ref, wp1, bp1, wp2, ww2, bw2, gw_, betaw,
                       W1H, VlinH, aff, stat, out);
}